// Round 14
// baseline (16240.588 us; speedup 1.0000x reference)
//
#include <hip/hip_runtime.h>
#include <math.h>

#define NBLK 256
#define NTHR 256
#define FLAGSTRIDE 16   // 64B per sub-barrier arrival-flag line
#define RELSTRIDE  32   // 128B per sub-barrier release line
#define NREL2      4    // release lines (sub barrier)
#define NTAGREP    8    // replicated tag columns (main barrier)

// ---------------- workspace layout (float offsets) ----------------
constexpr int OFF_Z    = 0;                      // z0 (2048) — read once
constexpr int OFF_XLIN = OFF_Z + 4096;           // 2048
constexpr int OFF_ZTH  = OFF_XLIN + 2048;        // 2048 tanh(xlin)
constexpr int OFF_G    = OFF_ZTH + 2048;         // 2048 gradient g
constexpr int OFF_HID  = OFF_G + 2048 + 3*2048;  // 4096
constexpr int OFF_H2   = OFF_HID + 4096;         // 512
constexpr int OFF_H3   = OFF_H2 + 512;           // 512
constexpr int OFF_G3   = OFF_H3 + 512;           // 512 (g2 after silu')
constexpr int OFF_WV   = OFF_G3 + 512;           // 4096 w vec
constexpr int OFF_A    = OFF_WV + 4096;          // 4096 A = w*w
constexpr int OFF_S    = OFF_A + 4096;           // 4096 S = expm(A)-I
constexpr int OFF_S2   = OFF_S + 4096;           // 4096 squaring scratch
constexpr int OFF_TRAJ = OFF_S2 + 4096;          // 64*2048
constexpr int OFF_H3W  = OFF_TRAJ + 64*2048;     // 64*512
constexpr int OFF_WEST = OFF_H3W + 64*512;       // 64*4096
constexpr int OFF_LMAT = OFF_WEST + 64*4096;     // 4096
constexpr int OFF_D12W = OFF_LMAT + 4096;        // 512*2052 (padded stride)
constexpr int OFF_D12B = OFF_D12W + 512*2052;    // 512
constexpr int OFF_D12T = OFF_D12B + 512;         // 2049*512
constexpr int OFF_D3T  = OFF_D12T + 2049*512;    // 512*4096
constexpr int OFF_BAR  = OFF_D3T + 512*4096;     // barrier region (ints)

// barrier region (int offsets from OFF_BAR)
constexpr int B_TAG    = 0;                           // 8 replicas x 256 block tags
constexpr int B_SUBF   = NTAGREP*256;                 // sub arrival flags (64*16)
constexpr int B_SUBR   = B_SUBF + 64*FLAGSTRIDE;      // sub release lines
constexpr int B_TOTAL  = B_SUBR + NREL2*RELSTRIDE;

__device__ __forceinline__ float gld(const float* p){
  return __hip_atomic_load(p, __ATOMIC_RELAXED, __HIP_MEMORY_SCOPE_AGENT);
}
__device__ __forceinline__ void gst(float* p, float v){
  __hip_atomic_store(p, v, __ATOMIC_RELAXED, __HIP_MEMORY_SCOPE_AGENT);
}
__device__ __forceinline__ int gldi(const int* p){
  return __hip_atomic_load(p, __ATOMIC_RELAXED, __HIP_MEMORY_SCOPE_AGENT);
}
__device__ __forceinline__ void gsti(int* p, int v){
  __hip_atomic_store(p, v, __ATOMIC_RELAXED, __HIP_MEMORY_SCOPE_AGENT);
}

__device__ __forceinline__ float wredsum(float v){
#pragma unroll
  for (int o = 32; o > 0; o >>= 1) v += __shfl_down(v, o);
  return v;
}

__device__ __forceinline__ float dot4(float4 a, float4 b){
  return a.x*b.x + a.y*b.y + a.z*b.z + a.w*b.w;
}

// short dependent-FMA chain: throttles poll rate, keeps VALU warm
__device__ __forceinline__ void spinfma(float &x){
#pragma unroll
  for (int i = 0; i < 8; ++i) x = __builtin_fmaf(x, 1.0000001f, 1.0e-30f);
}
__device__ __forceinline__ void sinkf(float x){ asm volatile("" :: "v"(x)); }

// Replicated all-poll-all grid barrier (2 hops: store 8 replicas; poll own replica).
// Consumer block c polls replica column c&7: lane L checks 4 tags -> 256 total.
// Per-line poll pressure ~128 lane-reqs per ~0.75us load RT (R5-level, no meltdown).
// Loop shape = R6's proven-correct per-lane-disjoint + __all exit (no divergent
// dependent spins). Producers store via lanes 0..7 (straight-line, reconverges).
__device__ __forceinline__ void gsync(int* __restrict__ bar, int epoch){
  asm volatile("s_waitcnt vmcnt(0)" ::: "memory");  // drain this wave's data stores
  __syncthreads();
  int* tags = bar + B_TAG;
  const int t = threadIdx.x;
  if (t < 64){
    if (t < NTAGREP) gsti(&tags[t*256 + blockIdx.x], epoch);
    const int base = (blockIdx.x & (NTAGREP-1))*256 + t*4;
    float x = 1.f;
    for (;;){
      int a = gldi(&tags[base+0]);
      int b = gldi(&tags[base+1]);
      int c = gldi(&tags[base+2]);
      int d = gldi(&tags[base+3]);
      if (__all((a>=epoch) && (b>=epoch) && (c>=epoch) && (d>=epoch))) break;
      spinfma(x);
    }
    sinkf(x);
  }
  __syncthreads();
  __atomic_signal_fence(__ATOMIC_ACQUIRE);
}

// sub-barrier among blocks 0..63 (gather/release, rare path — unchanged semantics)
__device__ __forceinline__ void gsync64(int* __restrict__ bar, int epoch){
  asm volatile("s_waitcnt vmcnt(0)" ::: "memory");
  __syncthreads();
  int* flags = bar + B_SUBF;
  int* rel   = bar + B_SUBR;
  if (blockIdx.x == 0){
    const int t = threadIdx.x;
    float x = 1.f;
    if (t > 0 && t < 64){
      while (gldi(&flags[t*FLAGSTRIDE]) < epoch) spinfma(x);
    }
    sinkf(x);
    __syncthreads();
    if (t < NREL2) gsti(&rel[t*RELSTRIDE], epoch);
  } else {
    if (threadIdx.x < 64){
      if (threadIdx.x == 0) gsti(&flags[blockIdx.x*FLAGSTRIDE], epoch);
      int* myrel = &rel[(blockIdx.x & (NREL2-1))*RELSTRIDE];
      float x = 1.f;
      while (gldi(myrel) < epoch) spinfma(x);
      sinkf(x);
    }
    __syncthreads();
  }
  __atomic_signal_fence(__ATOMIC_ACQUIRE);
}

// ---------------- init kernels ----------------
__global__ void __launch_bounds__(256) k_init_z0(const float* __restrict__ iit, const float* __restrict__ iis,
        const float* __restrict__ encw, const float* __restrict__ encb, float* __restrict__ ws){
  __shared__ float ii[4096];
  const int tid = threadIdx.x;
  for (int e = tid; e < 4096; e += 256){
    int i = e >> 6, j = e & 63;
    float s = 0.f;
#pragma unroll
    for (int k = 0; k < 32; ++k) s += iit[i*32+k]*iis[k*64+j];
    ii[e] = s;
  }
  __syncthreads();
  for (int e = tid; e < 2048; e += 256){
    int i = e >> 5, k = e & 31;
    float s = encb[k];
#pragma unroll
    for (int j = 0; j < 64; ++j) s += ii[i*64+j]*encw[k*128+j];
#pragma unroll
    for (int j = 0; j < 64; ++j) s += ii[j*64+i]*encw[k*128+64+j];
    ws[OFF_Z + e] = fmaxf(s, 0.f);
  }
}

__global__ void __launch_bounds__(256) k_init_dec12(const float* __restrict__ d1w, const float* __restrict__ d1b,
        const float* __restrict__ d2w, const float* __restrict__ d2b, float* __restrict__ ws){
  __shared__ float a[8*512];
  const int tid = threadIdx.x;
  const int o0 = blockIdx.x*8;
  for (int e = tid; e < 8*512; e += 256) a[e] = d2w[(o0 + (e>>9))*512 + (e & 511)];
  __syncthreads();
  for (int c = tid; c < 2052; c += 256){
    float acc[8];
#pragma unroll
    for (int oo = 0; oo < 8; ++oo) acc[oo] = 0.f;
    if (c < 2049){
      for (int m = 0; m < 512; ++m){
        float v = d1w[m*2049 + c];
#pragma unroll
        for (int oo = 0; oo < 8; ++oo) acc[oo] += a[oo*512+m]*v;
      }
    }
#pragma unroll
    for (int oo = 0; oo < 8; ++oo) ws[OFF_D12W + (size_t)(o0+oo)*2052 + c] = acc[oo];
  }
  if (tid < 8){
    float s = 0.f;
    for (int m = 0; m < 512; ++m) s += a[tid*512+m]*d1b[m];
    ws[OFF_D12B + o0 + tid] = s + d2b[o0+tid];
  }
}

__global__ void __launch_bounds__(256) k_tr12(float* __restrict__ ws){
  __shared__ float tb[32][33];
  const int c0 = blockIdx.x*32, o0 = blockIdx.y*32;
  const int x = threadIdx.x & 31, y = threadIdx.x >> 5;
#pragma unroll
  for (int yy = y; yy < 32; yy += 8){
    int o = o0+yy, c = c0+x;
    tb[yy][x] = (c < 2049) ? ws[OFF_D12W + (size_t)o*2052 + c] : 0.f;
  }
  __syncthreads();
#pragma unroll
  for (int yy = y; yy < 32; yy += 8){
    int c = c0+yy, o = o0+x;
    if (c < 2049) ws[OFF_D12T + (size_t)c*512 + o] = tb[x][yy];
  }
}

__global__ void __launch_bounds__(256) k_tr3(const float* __restrict__ d3w, float* __restrict__ ws){
  __shared__ float tb[32][33];
  const int c0 = blockIdx.x*32, r0 = blockIdx.y*32;
  const int x = threadIdx.x & 31, y = threadIdx.x >> 5;
#pragma unroll
  for (int yy = y; yy < 32; yy += 8) tb[yy][x] = d3w[(size_t)(r0+yy)*512 + c0+x];
  __syncthreads();
#pragma unroll
  for (int yy = y; yy < 32; yy += 8) ws[OFF_D3T + (size_t)(c0+yy)*4096 + r0+x] = tb[x][yy];
}

__global__ void __launch_bounds__(256) k_init_lmat(const float* __restrict__ uw, const float* __restrict__ vw, float* __restrict__ ws){
  int o = blockIdx.x*256 + threadIdx.x;
  int a = o >> 6, bj = o & 63;
  float s = 0.f;
#pragma unroll
  for (int k = 0; k < 32; ++k) s += uw[k*64 + a]*vw[bj*32 + k];
  ws[OFF_LMAT + o] = s;
}

// ---------------- persistent grid-sync ODE kernel, register-resident weights ----------------
__global__ void __launch_bounds__(256, 1) k_ode(
    const float* __restrict__ l1w, const float* __restrict__ l1b,
    const float* __restrict__ l2w, const float* __restrict__ l2b,
    const float* __restrict__ d3w, const float* __restrict__ d3b,
    float* __restrict__ ws, int* __restrict__ bar)
{
  __shared__ __align__(16) float lds[8448];
  const int tid  = threadIdx.x;
  const int bid  = blockIdx.x;
  const int lane = tid & 63;
  const int wid  = tid >> 6;
  const float third = 1.0f/3.0f;
  int ep = 0, eps = 0;
  constexpr int RED = 8384;
  // per-block staging rotation: block b starts at cacheline b (16 floats/line)
  const int rot = bid << 4;

  // ---- one-time weight preload into registers ----
  float4 wl1[4][8];  float bl1[4];
  float4 wl2[2][16]; float bl2[2];
  float4 wu[24];     float bu[8];
#pragma unroll
  for (int q = 0; q < 8; ++q) bu[q] = 0.f;
#pragma unroll
  for (int q = 0; q < 4; ++q){
    const int r = bid*16 + wid*4 + q;
    bl1[q] = l1b[r];
#pragma unroll
    for (int m = 0; m < 8; ++m) wl1[q][m] = *(const float4*)(l1w + (size_t)r*2048 + 4*lane + 256*m);
  }
#pragma unroll
  for (int q = 0; q < 2; ++q){
    const int r = bid*8 + wid*2 + q;
    bl2[q] = l2b[r];
#pragma unroll
    for (int m = 0; m < 16; ++m) wl2[q][m] = *(const float4*)(l2w + (size_t)r*4096 + 4*lane + 256*m);
  }
  if (wid < 2){
    const int r = bid*2 + wid;
#pragma unroll
    for (int m = 0; m < 8; ++m)  wu[m]   = *(const float4*)(ws + OFF_D12W + (size_t)r*2052 + 4*lane + 256*m);
#pragma unroll
    for (int m = 0; m < 16; ++m) wu[8+m] = *(const float4*)(ws + OFF_D3T  + (size_t)r*4096 + 4*lane + 256*m);
    bu[0] = ws[OFF_D12B + r];
    bu[1] = ws[OFF_D12W + (size_t)r*2052 + 2048];   // t-coefficient
  } else {
    const int r4 = bid*16 + (wid-2)*8;
#pragma unroll
    for (int q = 0; q < 8; ++q){
      wu[2*q]   = *(const float4*)(d3w + (size_t)(r4+q)*512 + 4*lane);
      wu[2*q+1] = *(const float4*)(d3w + (size_t)(r4+q)*512 + 256 + 4*lane);
      bu[q] = d3b[r4+q];
    }
    const int r7 = bid*8 + (wid-2)*4;
#pragma unroll
    for (int q = 0; q < 4; ++q){
      wu[16+2*q] = *(const float4*)(ws + OFF_D12T + (size_t)(r7+q)*512 + 4*lane);
      wu[17+2*q] = *(const float4*)(ws + OFF_D12T + (size_t)(r7+q)*512 + 256 + 4*lane);
    }
  }

  // ---- block-local RK4 state ----
  float zloc[8], k1l[8], k2l[8], k3l[8];
#pragma unroll
  for (int m = 0; m < 8; ++m){
    zloc[m] = gld(&ws[OFF_Z + tid + 256*m]);
    k1l[m] = k2l[m] = k3l[m] = 0.f;
  }
  float hh_reg = 0.f;   // tr(E-I), carried from phase 6 to next phase 1

  for (int it = 0; it <= 252; ++it){
    const int step = it >> 2;
    const int s    = it & 3;

    // ---- phase 1: f/z elementwise (local state) + zeval into LDS + l1 matvec ----
    {
      if (it == 0){
#pragma unroll
        for (int m = 0; m < 8; ++m){
          const int e = tid + 256*m;
          lds[e] = zloc[m];
          if (bid == 0) gst(&ws[OFF_TRAJ + e], zloc[m]);
        }
      } else {
        float gl[8], xl[8];
        float gp = 0.f;
#pragma unroll
        for (int m = 0; m < 8; ++m){
          const int e = tid + 256*m;
          gl[m] = gld(&ws[OFF_G + e]);
          xl[m] = gld(&ws[OFF_XLIN + e]);
          gp += gl[m]*gl[m];
        }
        float gpw = wredsum(gp);
        if (lane == 0) lds[RED+wid] = gpw;
        __syncthreads();
        float gg = lds[RED] + lds[RED+1] + lds[RED+2] + lds[RED+3];
        float inv = (gg > 1e-30f) ? 1.0f/fmaxf(gg, 1e-30f) : 0.0f;
        const float ih = inv*hh_reg;
#pragma unroll
        for (int m = 0; m < 8; ++m){
          const int e = tid + 256*m;
          float f = xl[m] - gl[m]*ih;
          float ze;
          if (s == 1){
            k1l[m] = f; ze = zloc[m] + f*third;
          } else if (s == 2){
            k2l[m] = f; ze = zloc[m] + f - k1l[m]*third;
          } else if (s == 3){
            k3l[m] = f; ze = zloc[m] + k1l[m] - k2l[m] + f;
          } else {
            zloc[m] += (k1l[m] + 3.0f*(k2l[m]+k3l[m]) + f)*0.125f;
            ze = zloc[m];
            if (bid == 0) gst(&ws[OFF_TRAJ + step*2048 + e], zloc[m]);
          }
          lds[e] = ze;
        }
      }
      __syncthreads();
      if (it < 252){
        float s0 = 0.f, s1 = 0.f, s2 = 0.f, s3 = 0.f;
#pragma unroll
        for (int m = 0; m < 8; ++m){
          float4 zv = *(const float4*)&lds[4*lane + 256*m];
          s0 += dot4(wl1[0][m], zv);
          s1 += dot4(wl1[1][m], zv);
          s2 += dot4(wl1[2][m], zv);
          s3 += dot4(wl1[3][m], zv);
        }
        s0 = wredsum(s0); s1 = wredsum(s1); s2 = wredsum(s2); s3 = wredsum(s3);
        if (lane == 0){
          const int r = bid*16 + wid*4;
          gst(&ws[OFF_HID + r+0], tanhf(s0 + bl1[0]));
          gst(&ws[OFF_HID + r+1], tanhf(s1 + bl1[1]));
          gst(&ws[OFF_HID + r+2], tanhf(s2 + bl1[2]));
          gst(&ws[OFF_HID + r+3], tanhf(s3 + bl1[3]));
        }
      }
    }
    gsync(bar, ++ep);
    if (it == 252) break;

    const float tval = (float)(step+1) + (s==1 ? third : (s==2 ? 2.0f*third : (s==3 ? 1.0f : 0.0f)));

    // ---- phase 2: l2 matvec -> xlin, tanh(xlin) ----
    {
      // rotated staging: block b starts at line b -> spreads IF$ line bursts
      for (int i = tid; i < 4096; i += 256){ int e = (i + rot) & 4095; lds[e] = gld(&ws[OFF_HID+e]); }
      __syncthreads();
      float s0 = 0.f, s1 = 0.f;
#pragma unroll
      for (int m = 0; m < 16; ++m){
        float4 hv = *(const float4*)&lds[4*lane + 256*m];
        s0 += dot4(wl2[0][m], hv);
        s1 += dot4(wl2[1][m], hv);
      }
      s0 = wredsum(s0); s1 = wredsum(s1);
      if (lane == 0){
        const int r = bid*8 + wid*2;
        float xl0 = s0 + bl2[0], xl1 = s1 + bl2[1];
        gst(&ws[OFF_XLIN+r+0], xl0); gst(&ws[OFF_ZTH+r+0], tanhf(xl0));
        gst(&ws[OFF_XLIN+r+1], xl1); gst(&ws[OFF_ZTH+r+1], tanhf(xl1));
      }
    }
    gsync(bar, ++ep);

    // ---- phase 3: dec12 matvec -> h2, h3=silu(h2) (waves 0,1) ----
    {
      for (int i = tid; i < 2048; i += 256){ int e = (i + rot) & 2047; lds[e] = gld(&ws[OFF_ZTH+e]); }
      __syncthreads();
      if (wid < 2){
        float sum = 0.f;
#pragma unroll
        for (int m = 0; m < 8; ++m){
          float4 zv = *(const float4*)&lds[4*lane + 256*m];
          sum += dot4(wu[m], zv);
        }
        sum = wredsum(sum);
        if (lane == 0){
          const int r = bid*2 + wid;
          sum += bu[1]*tval + bu[0];
          float sg = 1.0f/(1.0f+expf(-sum));
          gst(&ws[OFF_H2+r], sum);
          gst(&ws[OFF_H3+r], sum*sg);
        }
      }
    }
    gsync(bar, ++ep);

    // ---- phase 4: dec3 matvec -> wvec, A (waves 2,3) ----
    {
      { int e = (tid*2 + rot) & 511;       // 2 elems/thread, rotated
        lds[e] = gld(&ws[OFF_H3+e]);
        int e2 = (tid*2 + 1 + rot) & 511;
        lds[e2] = gld(&ws[OFF_H3+e2]); }
      __syncthreads();
      if (wid >= 2){
        float4 hv0 = *(const float4*)&lds[4*lane];
        float4 hv1 = *(const float4*)&lds[256 + 4*lane];
        const int r4 = bid*16 + (wid-2)*8;
#pragma unroll
        for (int q = 0; q < 8; ++q){
          float sum = dot4(wu[2*q], hv0) + dot4(wu[2*q+1], hv1);
          sum = wredsum(sum);
          if (lane == 0){
            float wvv = sum + bu[q];
            gst(&ws[OFF_WV+r4+q], wvv);
            gst(&ws[OFF_A+r4+q], wvv*wvv);
          }
        }
      }
    }
    gsync(bar, ++ep);

    // ---- phase 5: expm via scaled order-8 Taylor (blocks 0..63); others prestage 2*wv ----
    int ssc = 0;
    if (bid < 64){
      const int rot5 = bid << 6;   // 64 blocks spread over 256 lines
      for (int i = tid; i < 4096; i += 256){ int e = (i + rot5) & 4095; lds[(e>>6)*65 + (e&63)] = gld(&ws[OFF_A+e]); }
      __syncthreads();
      if (tid < 64){
        float rs = 0.f;
#pragma unroll
        for (int j = 0; j < 64; ++j) rs += lds[tid*65+j];
        lds[4224+tid] = rs;
      }
      __syncthreads();
      float th = 0.f;
#pragma unroll
      for (int j = 0; j < 64; ++j) th = fmaxf(th, lds[4224+j]);
      if (th > 0.25f){
        ssc = (int)ceilf(log2f(th*4.0f));
        if (ssc < 1) ssc = 1;
        if (ssc > 24) ssc = 24;
      }
      const float scl = exp2f((float)(-ssc));
      for (int e = tid; e < 4096; e += 256) lds[(e>>6)*65 + (e&63)] *= scl;
      __syncthreads();
      float cur0 = (tid < 64) ? lds[bid*65+tid] : 0.f;
      if (tid < 64) lds[4288+tid] = cur0;
      float srow = cur0;
      __syncthreads();
      const float invf[7] = {0.5f, 1.0f/6.0f, 1.0f/24.0f, 1.0f/120.0f, 1.0f/720.0f, 1.0f/5040.0f, 1.0f/40320.0f};
#pragma unroll
      for (int k = 0; k < 7; ++k){
        float nv = 0.f;
        if (tid < 64){
#pragma unroll
          for (int m = 0; m < 64; ++m) nv += lds[4288+m]*lds[m*65+tid];
        }
        __syncthreads();
        if (tid < 64) lds[4288+tid] = nv;
        srow += nv*invf[k];
        __syncthreads();
      }
      const int pb = ssc & 1;
      if (tid < 64) gst(&ws[(pb ? OFF_S2 : OFF_S) + bid*64 + tid], srow);
      // prestage 2*wv for phase 6 (rotated)
      for (int i = tid; i < 4096; i += 256){ int e = (i + rot5) & 4095; lds[4352+e] = 2.0f*gld(&ws[OFF_WV+e]); }
      // squaring chain (rare): sub-barrier among blocks 0..63 only
      for (int q = 0; q < ssc; ++q){
        gsync64(bar, ++eps);
        const int src = (ssc - q) & 1;
        const int so = src ? OFF_S2 : OFF_S;
        const int dofs = src ? OFF_S : OFF_S2;
        for (int i = tid; i < 4096; i += 256){ int e = (i + rot5) & 4095; lds[(e>>6)*65 + (e&63)] = gld(&ws[so+e]); }
        __syncthreads();
        if (tid < 64) lds[4288+tid] = lds[bid*65+tid];
        __syncthreads();
        if (tid < 64){
          float nv = 0.f;
#pragma unroll
          for (int m = 0; m < 64; ++m) nv += lds[4288+m]*lds[m*65+tid];
          nv += 2.0f*lds[4288+tid];
          gst(&ws[dofs + bid*64 + tid], nv);
        }
        __syncthreads();
      }
    } else {
      for (int i = tid; i < 4096; i += 256){ int e = (i + rot) & 4095; lds[4352+e] = 2.0f*gld(&ws[OFF_WV+e]); }
    }
    gsync(bar, ++ep);

    // ---- phase 6: Gvec = 2w ∘ Eᵀ ; g2 = silu'(h2) ∘ (dec3ᵀ @ Gvec) (waves 0,1); tr(S)->hh_reg ----
    {
      for (int i = tid; i < 4096; i += 256){ int e = (i + rot) & 4095; lds[(e>>6)*65 + (e&63)] = gld(&ws[OFF_S+e]); }
      __syncthreads();
      if (tid < 64) lds[4160+tid] = lds[tid*65+tid];   // diag(S)
      for (int e = tid; e < 4096; e += 256){
        const int i = e >> 6, j = e & 63;
        float Eji = lds[j*65+i] + ((i==j) ? 1.0f : 0.0f);
        lds[4352+e] *= Eji;                            // (2*wv) * Eji, prestaged in phase 5
      }
      __syncthreads();
      {
        float hh = 0.f;
#pragma unroll
        for (int k = 0; k < 64; ++k) hh += lds[4160+k];
        hh_reg = hh;
      }
      if (wid < 2){
        float sum = 0.f;
#pragma unroll
        for (int m = 0; m < 16; ++m){
          float4 gv = *(const float4*)&lds[4352 + 4*lane + 256*m];
          sum += dot4(wu[8+m], gv);
        }
        sum = wredsum(sum);
        if (lane == 0){
          const int r = bid*2 + wid;
          float h2v = gld(&ws[OFF_H2+r]);
          float sg = 1.0f/(1.0f+expf(-h2v));
          gst(&ws[OFF_G3+r], sum*(sg*(1.0f + h2v*(1.0f-sg))));
        }
      }
    }
    gsync(bar, ++ep);

    // ---- phase 7: g = tanh' ∘ (dec12ᵀ @ g2) (waves 2,3) ----
    {
      { int e = (tid*2 + rot) & 511;
        lds[e] = gld(&ws[OFF_G3+e]);
        int e2 = (tid*2 + 1 + rot) & 511;
        lds[e2] = gld(&ws[OFF_G3+e2]); }
      __syncthreads();
      if (wid >= 2){
        float4 gv0 = *(const float4*)&lds[4*lane];
        float4 gv1 = *(const float4*)&lds[256 + 4*lane];
        const int r7 = bid*8 + (wid-2)*4;
#pragma unroll
        for (int q = 0; q < 4; ++q){
          float sum = dot4(wu[16+2*q], gv0) + dot4(wu[17+2*q], gv1);
          sum = wredsum(sum);
          if (lane == 0){
            float thv = gld(&ws[OFF_ZTH+r7+q]);
            gst(&ws[OFF_G+r7+q], sum*(1.0f - thv*thv));
          }
        }
      }
    }
    gsync(bar, ++ep);
  }

  // ---- west pass 1: dec12 over all t ----
  {
    const int t = bid >> 2;
    const int quad = bid & 3;
    for (int e = tid; e < 2048; e += 256) lds[e] = tanhf(gld(&ws[OFF_TRAJ + t*2048 + e]));
    __syncthreads();
    const float tw = (float)(t+1);
    for (int q = 0; q < 32; ++q){
      const int r = quad*128 + wid*32 + q;
      const float* wrow = ws + OFF_D12W + (size_t)r*2052;
      const float4* wr = (const float4*)wrow;
      float sum = 0.f;
#pragma unroll
      for (int m = 0; m < 8; ++m){
        float4 wv = wr[lane + 64*m];
        float4 zv = *(const float4*)&lds[(lane + 64*m)*4];
        sum += wv.x*zv.x + wv.y*zv.y + wv.z*zv.z + wv.w*zv.w;
      }
      sum = wredsum(sum);
      if (lane == 0){
        sum += wrow[2048]*tw + ws[OFF_D12B+r];
        float sg = 1.0f/(1.0f+expf(-sum));
        gst(&ws[OFF_H3W + t*512 + r], sum*sg);
      }
    }
  }
  gsync(bar, ++ep);
  // ---- west pass 2: dec3 over all t ----
  {
    const int t = bid >> 2;
    const int quad = bid & 3;
    for (int e = tid; e < 512; e += 256) lds[e] = gld(&ws[OFF_H3W + t*512 + e]);
    __syncthreads();
    for (int q = 0; q < 256; ++q){
      const int r = quad*1024 + wid*256 + q;
      const float4* wr = (const float4*)(d3w + (size_t)r*512);
      float sum = 0.f;
#pragma unroll
      for (int m = 0; m < 2; ++m){
        float4 wv = wr[lane + 64*m];
        float4 hv = *(const float4*)&lds[(lane + 64*m)*4];
        sum += wv.x*hv.x + wv.y*hv.y + wv.z*hv.z + wv.w*hv.w;
      }
      sum = wredsum(sum);
      if (lane == 0) ws[OFF_WEST + t*4096 + r] = sum + d3b[r];   // cross-kernel only
    }
  }
}

// ---------------- output kernel: out[b,t] = x[b,t]@W_t + x[b,t-1]@L ----------------
__global__ void __launch_bounds__(256) k_out(const float* __restrict__ x,
        const float* __restrict__ ws, float* __restrict__ out)
{
  __shared__ __align__(16) float Wbuf[4096];
  __shared__ __align__(16) float Xbuf[64*65];
  const int tid = threadIdx.x;
  const int t  = blockIdx.x & 63;
  const int bb = blockIdx.x >> 6;
  const int k0 = (tid & 15)*4;
  const int b0 = (tid >> 4)*4;
  const float* xbase = x + ((size_t)bb*64)*4096;

  float acc[4][4];
#pragma unroll
  for (int j = 0; j < 4; ++j)
#pragma unroll
    for (int c = 0; c < 4; ++c) acc[j][c] = 0.f;

  for (int e = tid; e < 4096; e += 256) Wbuf[e] = ws[OFF_WEST + t*4096 + e];
  for (int e = tid; e < 4096; e += 256){ int row = e>>6, col = e&63; Xbuf[row*65+col] = xbase[(size_t)row*4096 + t*64 + col]; }
  __syncthreads();
  for (int d = 0; d < 64; ++d){
    float4 wv = *(const float4*)&Wbuf[d*64 + k0];
#pragma unroll
    for (int j = 0; j < 4; ++j){
      float xv = Xbuf[(b0+j)*65 + d];
      acc[j][0] += xv*wv.x; acc[j][1] += xv*wv.y; acc[j][2] += xv*wv.z; acc[j][3] += xv*wv.w;
    }
  }
  if (t > 0){
    __syncthreads();
    for (int e = tid; e < 4096; e += 256) Wbuf[e] = ws[OFF_LMAT + e];
    for (int e = tid; e < 4096; e += 256){ int row = e>>6, col = e&63; Xbuf[row*65+col] = xbase[(size_t)row*4096 + (t-1)*64 + col]; }
    __syncthreads();
    for (int d = 0; d < 64; ++d){
      float4 wv = *(const float4*)&Wbuf[d*64 + k0];
#pragma unroll
      for (int j = 0; j < 4; ++j){
        float xv = Xbuf[(b0+j)*65 + d];
        acc[j][0] += xv*wv.x; acc[j][1] += xv*wv.y; acc[j][2] += xv*wv.z; acc[j][3] += xv*wv.w;
      }
    }
  }
#pragma unroll
  for (int j = 0; j < 4; ++j){
    float4 o4; o4.x = acc[j][0]; o4.y = acc[j][1]; o4.z = acc[j][2]; o4.w = acc[j][3];
    *(float4*)&out[((size_t)(bb*64 + b0 + j))*4096 + t*64 + k0] = o4;
  }
}

// ---------------- host launcher ----------------
extern "C" void kernel_launch(void* const* d_in, const int* in_sizes, int n_in,
                              void* d_out, int out_size, void* d_ws, size_t ws_size,
                              hipStream_t stream) {
  (void)in_sizes; (void)n_in; (void)out_size; (void)ws_size;
  const float* x    = (const float*)d_in[0];
  const float* iit  = (const float*)d_in[1];
  const float* iis  = (const float*)d_in[2];
  const float* encw = (const float*)d_in[3];
  const float* encb = (const float*)d_in[4];
  const float* l1w  = (const float*)d_in[5];
  const float* l1b  = (const float*)d_in[6];
  const float* l2w  = (const float*)d_in[7];
  const float* l2b  = (const float*)d_in[8];
  const float* d1w  = (const float*)d_in[9];
  const float* d1b  = (const float*)d_in[10];
  const float* d2w  = (const float*)d_in[11];
  const float* d2b  = (const float*)d_in[12];
  const float* d3w  = (const float*)d_in[13];
  const float* d3b  = (const float*)d_in[14];
  const float* uw   = (const float*)d_in[15];
  const float* vw   = (const float*)d_in[16];
  float* out = (float*)d_out;
  float* ws  = (float*)d_ws;
  int* bar   = (int*)(ws + OFF_BAR);

  hipMemsetAsync(bar, 0, B_TOTAL*sizeof(int), stream);
  k_init_z0<<<1, 256, 0, stream>>>(iit, iis, encw, encb, ws);
  k_init_dec12<<<64, 256, 0, stream>>>(d1w, d1b, d2w, d2b, ws);
  k_tr12<<<dim3(65,16), 256, 0, stream>>>(ws);
  k_tr3<<<dim3(16,128), 256, 0, stream>>>(d3w, ws);
  k_init_lmat<<<16, 256, 0, stream>>>(uw, vw, ws);

  k_ode<<<NBLK, NTHR, 0, stream>>>(l1w, l1b, l2w, l2b, d3w, d3b, ws, bar);

  k_out<<<4096, 256, 0, stream>>>(x, ws, out);
}

// Round 16
// 14400.009 us; speedup vs baseline: 1.1278x; 1.1278x over previous
//
#include <hip/hip_runtime.h>
#include <math.h>

#define NBLK 256
#define NTHR 256
#define FLAGSTRIDE 16   // 64B per arrival-flag line
#define RELSTRIDE  32   // 128B per release line
#define NREL       16   // release lines (main barrier)
#define NREL2      4    // release lines (sub barrier)

// ---------------- workspace layout (float offsets) ----------------
constexpr int OFF_Z    = 0;                      // z0 (2048) — read once
constexpr int OFF_XLIN = OFF_Z + 4096;           // 2048
constexpr int OFF_ZTH  = OFF_XLIN + 2048;        // 2048 tanh(xlin)
constexpr int OFF_G    = OFF_ZTH + 2048;         // 2048 gradient g
constexpr int OFF_HID  = OFF_G + 2048 + 3*2048;  // 4096
constexpr int OFF_H2   = OFF_HID + 4096;         // 512
constexpr int OFF_H3   = OFF_H2 + 512;           // 512 (retired; kept for layout)
constexpr int OFF_G3   = OFF_H3 + 512;           // 512 (retired; kept for layout)
constexpr int OFF_WV   = OFF_G3 + 512;           // 4096 w vec
constexpr int OFF_A    = OFF_WV + 4096;          // 4096 A = w*w
constexpr int OFF_S    = OFF_A + 4096;           // 4096 S = expm(A)-I
constexpr int OFF_S2   = OFF_S + 4096;           // 4096 squaring scratch
constexpr int OFF_TRAJ = OFF_S2 + 4096;          // 64*2048
constexpr int OFF_H3W  = OFF_TRAJ + 64*2048;     // 64*512
constexpr int OFF_WEST = OFF_H3W + 64*512;       // 64*4096
constexpr int OFF_LMAT = OFF_WEST + 64*4096;     // 4096
constexpr int OFF_D12W = OFF_LMAT + 4096;        // 512*2052 (padded stride)
constexpr int OFF_D12B = OFF_D12W + 512*2052;    // 512
constexpr int OFF_D12T = OFF_D12B + 512;         // 2049*512
constexpr int OFF_D3T  = OFF_D12T + 2049*512;    // 512*4096
constexpr int OFF_BAR  = OFF_D3T + 512*4096;     // barrier region (ints)

// barrier region (int offsets from OFF_BAR)
constexpr int BAR_REL    = 256*FLAGSTRIDE;             // main release lines
constexpr int BAR_SUB    = BAR_REL + NREL*RELSTRIDE;   // sub arrival flags
constexpr int BAR_SUBREL = BAR_SUB + 64*FLAGSTRIDE;    // sub release lines
constexpr int BAR_END    = BAR_SUBREL + NREL2*RELSTRIDE;
constexpr int BAR_TH3    = (BAR_END + 1) & ~1;         // u64 tagged H3 [512]
constexpr int BAR_TG3    = BAR_TH3 + 512*2;            // u64 tagged G3 [512]
constexpr int BAR_TOTAL  = BAR_TG3 + 512*2;

__device__ __forceinline__ float gld(const float* p){
  return __hip_atomic_load(p, __ATOMIC_RELAXED, __HIP_MEMORY_SCOPE_AGENT);
}
__device__ __forceinline__ void gst(float* p, float v){
  __hip_atomic_store(p, v, __ATOMIC_RELAXED, __HIP_MEMORY_SCOPE_AGENT);
}
__device__ __forceinline__ int gldi(const int* p){
  return __hip_atomic_load(p, __ATOMIC_RELAXED, __HIP_MEMORY_SCOPE_AGENT);
}
__device__ __forceinline__ void gsti(int* p, int v){
  __hip_atomic_store(p, v, __ATOMIC_RELAXED, __HIP_MEMORY_SCOPE_AGENT);
}
// tagged-data primitives: {tag,value} packed in one atomic u64 (no torn reads)
__device__ __forceinline__ unsigned long long tld(const unsigned long long* p){
  return __hip_atomic_load(p, __ATOMIC_RELAXED, __HIP_MEMORY_SCOPE_AGENT);
}
__device__ __forceinline__ void tst(unsigned long long* p, float v, int tag){
  unsigned long long u = ((unsigned long long)(unsigned)tag << 32) | (unsigned long long)__float_as_uint(v);
  __hip_atomic_store(p, u, __ATOMIC_RELAXED, __HIP_MEMORY_SCOPE_AGENT);
}

__device__ __forceinline__ float wredsum(float v){
#pragma unroll
  for (int o = 32; o > 0; o >>= 1) v += __shfl_down(v, o);
  return v;
}

__device__ __forceinline__ float dot4(float4 a, float4 b){
  return a.x*b.x + a.y*b.y + a.z*b.z + a.w*b.w;
}

// short dependent-FMA chain: throttles poll rate, keeps VALU warm
__device__ __forceinline__ void spinfma(float &x){
#pragma unroll
  for (int i = 0; i < 8; ++i) x = __builtin_fmaf(x, 1.0000001f, 1.0e-30f);
}
__device__ __forceinline__ void sinkf(float x){ asm volatile("" :: "v"(x)); }

// gather/release grid barrier (R10/R13-proven topology, unchanged semantics).
__device__ __forceinline__ void gsync(int* __restrict__ bar, int epoch){
  asm volatile("s_waitcnt vmcnt(0)" ::: "memory");  // drain this wave's data stores
  __syncthreads();
  int* rel = bar + BAR_REL;
  if (blockIdx.x == 0){
    const int t = threadIdx.x;
    float x = 1.f;
    if (t > 0){
      while (gldi(&bar[t*FLAGSTRIDE]) < epoch) spinfma(x);
    }
    sinkf(x);
    __syncthreads();
    if (t < NREL) gsti(&rel[t*RELSTRIDE], epoch);
  } else {
    if (threadIdx.x < 64){
      if (threadIdx.x == 0) gsti(&bar[blockIdx.x*FLAGSTRIDE], epoch);
      int* myrel = &rel[(blockIdx.x & (NREL-1))*RELSTRIDE];
      float x = 1.f;
      while (gldi(myrel) < epoch) spinfma(x);   // wave-uniform poll
      sinkf(x);
    }
    __syncthreads();
  }
  __atomic_signal_fence(__ATOMIC_ACQUIRE);
}

// sub-barrier among blocks 0..63 (same discipline)
__device__ __forceinline__ void gsync64(int* __restrict__ bar, int epoch){
  asm volatile("s_waitcnt vmcnt(0)" ::: "memory");
  __syncthreads();
  int* flags = bar + BAR_SUB;
  int* rel   = bar + BAR_SUBREL;
  if (blockIdx.x == 0){
    const int t = threadIdx.x;
    float x = 1.f;
    if (t > 0 && t < 64){
      while (gldi(&flags[t*FLAGSTRIDE]) < epoch) spinfma(x);
    }
    sinkf(x);
    __syncthreads();
    if (t < NREL2) gsti(&rel[t*RELSTRIDE], epoch);
  } else {
    if (threadIdx.x < 64){
      if (threadIdx.x == 0) gsti(&flags[blockIdx.x*FLAGSTRIDE], epoch);
      int* myrel = &rel[(blockIdx.x & (NREL2-1))*RELSTRIDE];
      float x = 1.f;
      while (gldi(myrel) < epoch) spinfma(x);
      sinkf(x);
    }
    __syncthreads();
  }
  __atomic_signal_fence(__ATOMIC_ACQUIRE);
}

// ---------------- init kernels ----------------
__global__ void __launch_bounds__(256) k_init_z0(const float* __restrict__ iit, const float* __restrict__ iis,
        const float* __restrict__ encw, const float* __restrict__ encb, float* __restrict__ ws){
  __shared__ float ii[4096];
  const int tid = threadIdx.x;
  for (int e = tid; e < 4096; e += 256){
    int i = e >> 6, j = e & 63;
    float s = 0.f;
#pragma unroll
    for (int k = 0; k < 32; ++k) s += iit[i*32+k]*iis[k*64+j];
    ii[e] = s;
  }
  __syncthreads();
  for (int e = tid; e < 2048; e += 256){
    int i = e >> 5, k = e & 31;
    float s = encb[k];
#pragma unroll
    for (int j = 0; j < 64; ++j) s += ii[i*64+j]*encw[k*128+j];
#pragma unroll
    for (int j = 0; j < 64; ++j) s += ii[j*64+i]*encw[k*128+64+j];
    ws[OFF_Z + e] = fmaxf(s, 0.f);
  }
}

__global__ void __launch_bounds__(256) k_init_dec12(const float* __restrict__ d1w, const float* __restrict__ d1b,
        const float* __restrict__ d2w, const float* __restrict__ d2b, float* __restrict__ ws){
  __shared__ float a[8*512];
  const int tid = threadIdx.x;
  const int o0 = blockIdx.x*8;
  for (int e = tid; e < 8*512; e += 256) a[e] = d2w[(o0 + (e>>9))*512 + (e & 511)];
  __syncthreads();
  for (int c = tid; c < 2052; c += 256){
    float acc[8];
#pragma unroll
    for (int oo = 0; oo < 8; ++oo) acc[oo] = 0.f;
    if (c < 2049){
      for (int m = 0; m < 512; ++m){
        float v = d1w[m*2049 + c];
#pragma unroll
        for (int oo = 0; oo < 8; ++oo) acc[oo] += a[oo*512+m]*v;
      }
    }
#pragma unroll
    for (int oo = 0; oo < 8; ++oo) ws[OFF_D12W + (size_t)(o0+oo)*2052 + c] = acc[oo];
  }
  if (tid < 8){
    float s = 0.f;
    for (int m = 0; m < 512; ++m) s += a[tid*512+m]*d1b[m];
    ws[OFF_D12B + o0 + tid] = s + d2b[o0+tid];
  }
}

__global__ void __launch_bounds__(256) k_tr12(float* __restrict__ ws){
  __shared__ float tb[32][33];
  const int c0 = blockIdx.x*32, o0 = blockIdx.y*32;
  const int x = threadIdx.x & 31, y = threadIdx.x >> 5;
#pragma unroll
  for (int yy = y; yy < 32; yy += 8){
    int o = o0+yy, c = c0+x;
    tb[yy][x] = (c < 2049) ? ws[OFF_D12W + (size_t)o*2052 + c] : 0.f;
  }
  __syncthreads();
#pragma unroll
  for (int yy = y; yy < 32; yy += 8){
    int c = c0+yy, o = o0+x;
    if (c < 2049) ws[OFF_D12T + (size_t)c*512 + o] = tb[x][yy];
  }
}

__global__ void __launch_bounds__(256) k_tr3(const float* __restrict__ d3w, float* __restrict__ ws){
  __shared__ float tb[32][33];
  const int c0 = blockIdx.x*32, r0 = blockIdx.y*32;
  const int x = threadIdx.x & 31, y = threadIdx.x >> 5;
#pragma unroll
  for (int yy = y; yy < 32; yy += 8) tb[yy][x] = d3w[(size_t)(r0+yy)*512 + c0+x];
  __syncthreads();
#pragma unroll
  for (int yy = y; yy < 32; yy += 8) ws[OFF_D3T + (size_t)(c0+yy)*4096 + r0+x] = tb[x][yy];
}

__global__ void __launch_bounds__(256) k_init_lmat(const float* __restrict__ uw, const float* __restrict__ vw, float* __restrict__ ws){
  int o = blockIdx.x*256 + threadIdx.x;
  int a = o >> 6, bj = o & 63;
  float s = 0.f;
#pragma unroll
  for (int k = 0; k < 32; ++k) s += uw[k*64 + a]*vw[bj*32 + k];
  ws[OFF_LMAT + o] = s;
}

// ---------------- persistent grid-sync ODE kernel, register-resident weights ----------------
__global__ void __launch_bounds__(256, 1) k_ode(
    const float* __restrict__ l1w, const float* __restrict__ l1b,
    const float* __restrict__ l2w, const float* __restrict__ l2b,
    const float* __restrict__ d3w, const float* __restrict__ d3b,
    float* __restrict__ ws, int* __restrict__ bar)
{
  // 8448 working + 16 persist slots (indices 8448.. never touched by phases)
  __shared__ __align__(16) float lds[8464];
  const int tid  = threadIdx.x;
  const int bid  = blockIdx.x;
  const int lane = tid & 63;
  const int wid  = tid >> 6;
  const float third = 1.0f/3.0f;
  int ep = 0, eps = 0;
  constexpr int RED = 8384;       // transient reduction scratch (phase 1 only)
  constexpr int PERSIST = 8448;   // persisted h2 (0,1) + own zth rows (2..9)
  const int rot = bid << 4;
  unsigned long long* TH3 = (unsigned long long*)(bar + BAR_TH3);
  unsigned long long* TG3 = (unsigned long long*)(bar + BAR_TG3);

  // ---- one-time weight preload into registers ----
  float4 wl1[4][8];  float bl1[4];
  float4 wl2[2][16]; float bl2[2];
  float4 wu[24];     float bu[8];
#pragma unroll
  for (int q = 0; q < 8; ++q) bu[q] = 0.f;
#pragma unroll
  for (int q = 0; q < 4; ++q){
    const int r = bid*16 + wid*4 + q;
    bl1[q] = l1b[r];
#pragma unroll
    for (int m = 0; m < 8; ++m) wl1[q][m] = *(const float4*)(l1w + (size_t)r*2048 + 4*lane + 256*m);
  }
#pragma unroll
  for (int q = 0; q < 2; ++q){
    const int r = bid*8 + wid*2 + q;
    bl2[q] = l2b[r];
#pragma unroll
    for (int m = 0; m < 16; ++m) wl2[q][m] = *(const float4*)(l2w + (size_t)r*4096 + 4*lane + 256*m);
  }
  if (wid < 2){
    const int r = bid*2 + wid;
#pragma unroll
    for (int m = 0; m < 8; ++m)  wu[m]   = *(const float4*)(ws + OFF_D12W + (size_t)r*2052 + 4*lane + 256*m);
#pragma unroll
    for (int m = 0; m < 16; ++m) wu[8+m] = *(const float4*)(ws + OFF_D3T  + (size_t)r*4096 + 4*lane + 256*m);
    bu[0] = ws[OFF_D12B + r];
    bu[1] = ws[OFF_D12W + (size_t)r*2052 + 2048];   // t-coefficient
  } else {
    const int r4 = bid*16 + (wid-2)*8;
#pragma unroll
    for (int q = 0; q < 8; ++q){
      wu[2*q]   = *(const float4*)(d3w + (size_t)(r4+q)*512 + 4*lane);
      wu[2*q+1] = *(const float4*)(d3w + (size_t)(r4+q)*512 + 256 + 4*lane);
      bu[q] = d3b[r4+q];
    }
    const int r7 = bid*8 + (wid-2)*4;
#pragma unroll
    for (int q = 0; q < 4; ++q){
      wu[16+2*q] = *(const float4*)(ws + OFF_D12T + (size_t)(r7+q)*512 + 4*lane);
      wu[17+2*q] = *(const float4*)(ws + OFF_D12T + (size_t)(r7+q)*512 + 256 + 4*lane);
    }
  }

  // ---- block-local RK4 state ----
  float zloc[8], k1l[8], k2l[8], k3l[8];
#pragma unroll
  for (int m = 0; m < 8; ++m){
    zloc[m] = gld(&ws[OFF_Z + tid + 256*m]);
    k1l[m] = k2l[m] = k3l[m] = 0.f;
  }
  float hh_reg = 0.f;   // tr(E-I), carried from phase 6 to next phase 1

  for (int it = 0; it <= 252; ++it){
    const int step = it >> 2;
    const int s    = it & 3;
    const int dtag = it + 1;    // tag for this eval's tagged exchanges

    // ---- phase 1: f/z elementwise (local state) + zeval into LDS + l1 matvec ----
    {
      if (it == 0){
#pragma unroll
        for (int m = 0; m < 8; ++m){
          const int e = tid + 256*m;
          lds[e] = zloc[m];
          if (bid == 0) gst(&ws[OFF_TRAJ + e], zloc[m]);
        }
      } else {
        float gl[8], xl[8];
        float gp = 0.f;
#pragma unroll
        for (int m = 0; m < 8; ++m){
          const int e = tid + 256*m;
          gl[m] = gld(&ws[OFF_G + e]);
          xl[m] = gld(&ws[OFF_XLIN + e]);
          gp += gl[m]*gl[m];
        }
        float gpw = wredsum(gp);
        if (lane == 0) lds[RED+wid] = gpw;
        __syncthreads();
        float gg = lds[RED] + lds[RED+1] + lds[RED+2] + lds[RED+3];
        float inv = (gg > 1e-30f) ? 1.0f/fmaxf(gg, 1e-30f) : 0.0f;
        const float ih = inv*hh_reg;
#pragma unroll
        for (int m = 0; m < 8; ++m){
          const int e = tid + 256*m;
          float f = xl[m] - gl[m]*ih;
          float ze;
          if (s == 1){
            k1l[m] = f; ze = zloc[m] + f*third;
          } else if (s == 2){
            k2l[m] = f; ze = zloc[m] + f - k1l[m]*third;
          } else if (s == 3){
            k3l[m] = f; ze = zloc[m] + k1l[m] - k2l[m] + f;
          } else {
            zloc[m] += (k1l[m] + 3.0f*(k2l[m]+k3l[m]) + f)*0.125f;
            ze = zloc[m];
            if (bid == 0) gst(&ws[OFF_TRAJ + step*2048 + e], zloc[m]);
          }
          lds[e] = ze;
        }
      }
      __syncthreads();
      if (it < 252){
        float s0 = 0.f, s1 = 0.f, s2 = 0.f, s3 = 0.f;
#pragma unroll
        for (int m = 0; m < 8; ++m){
          float4 zv = *(const float4*)&lds[4*lane + 256*m];
          s0 += dot4(wl1[0][m], zv);
          s1 += dot4(wl1[1][m], zv);
          s2 += dot4(wl1[2][m], zv);
          s3 += dot4(wl1[3][m], zv);
        }
        s0 = wredsum(s0); s1 = wredsum(s1); s2 = wredsum(s2); s3 = wredsum(s3);
        if (lane == 0){
          const int r = bid*16 + wid*4;
          gst(&ws[OFF_HID + r+0], tanhf(s0 + bl1[0]));
          gst(&ws[OFF_HID + r+1], tanhf(s1 + bl1[1]));
          gst(&ws[OFF_HID + r+2], tanhf(s2 + bl1[2]));
          gst(&ws[OFF_HID + r+3], tanhf(s3 + bl1[3]));
        }
      }
    }
    gsync(bar, ++ep);
    if (it == 252) break;

    const float tval = (float)(step+1) + (s==1 ? third : (s==2 ? 2.0f*third : (s==3 ? 1.0f : 0.0f)));

    // ---- phase 2: l2 matvec -> xlin, tanh(xlin) ----
    {
      for (int i = tid; i < 4096; i += 256){ int e = (i + rot) & 4095; lds[e] = gld(&ws[OFF_HID+e]); }
      __syncthreads();
      float s0 = 0.f, s1 = 0.f;
#pragma unroll
      for (int m = 0; m < 16; ++m){
        float4 hv = *(const float4*)&lds[4*lane + 256*m];
        s0 += dot4(wl2[0][m], hv);
        s1 += dot4(wl2[1][m], hv);
      }
      s0 = wredsum(s0); s1 = wredsum(s1);
      if (lane == 0){
        const int r = bid*8 + wid*2;
        float xl0 = s0 + bl2[0], xl1 = s1 + bl2[1];
        gst(&ws[OFF_XLIN+r+0], xl0); gst(&ws[OFF_ZTH+r+0], tanhf(xl0));
        gst(&ws[OFF_XLIN+r+1], xl1); gst(&ws[OFF_ZTH+r+1], tanhf(xl1));
      }
    }
    gsync(bar, ++ep);

    // ---- phase 3: dec12 matvec -> h2 (persisted), h3 (tagged) ----
    {
      for (int i = tid; i < 2048; i += 256){ int e = (i + rot) & 2047; lds[e] = gld(&ws[OFF_ZTH+e]); }
      __syncthreads();
      // persist own 8 zth rows for phase 7's tanh' factor (dedicated region)
      if (tid < 8) lds[PERSIST+2+tid] = lds[bid*8 + tid];
      if (wid < 2){
        float sum = 0.f;
#pragma unroll
        for (int m = 0; m < 8; ++m){
          float4 zv = *(const float4*)&lds[4*lane + 256*m];
          sum += dot4(wu[m], zv);
        }
        sum = wredsum(sum);
        if (lane == 0){
          const int r = bid*2 + wid;
          sum += bu[1]*tval + bu[0];
          float sg = 1.0f/(1.0f+expf(-sum));
          lds[PERSIST+wid] = sum;                    // h2 block-local (self-consumed in P6)
          tst(&TH3[r], sum*sg, dtag);                // tagged h3 -> consumers poll
        }
      }
    }
    // NO grid barrier: P4 consumes tagged H3 directly

    // ---- phase 4: dec3 matvec -> wvec, A (waves 2,3); tagged-H3 staging ----
    {
      __syncthreads();   // protect lds[0..511] reuse within block
      {
        const int s0i = 2*tid, s1i = 2*tid+1;
        float x = 1.f;
        unsigned long long a, b;
        for (;;){
          a = tld(&TH3[s0i]);
          b = tld(&TH3[s1i]);
          if (__all(((int)(a>>32) >= dtag) && ((int)(b>>32) >= dtag))) break;
          spinfma(x);
        }
        sinkf(x);
        lds[s0i] = __uint_as_float((unsigned)a);
        lds[s1i] = __uint_as_float((unsigned)b);
      }
      __syncthreads();
      if (wid >= 2){
        float4 hv0 = *(const float4*)&lds[4*lane];
        float4 hv1 = *(const float4*)&lds[256 + 4*lane];
        const int r4 = bid*16 + (wid-2)*8;
#pragma unroll
        for (int q = 0; q < 8; ++q){
          float sum = dot4(wu[2*q], hv0) + dot4(wu[2*q+1], hv1);
          sum = wredsum(sum);
          if (lane == 0){
            float wvv = sum + bu[q];
            gst(&ws[OFF_WV+r4+q], wvv);
            gst(&ws[OFF_A+r4+q], wvv*wvv);
          }
        }
      }
    }
    gsync(bar, ++ep);

    // ---- phase 5: expm via scaled order-8 Taylor (blocks 0..63); others prestage 2*wv ----
    int ssc = 0;
    if (bid < 64){
      const int rot5 = bid << 6;
      for (int i = tid; i < 4096; i += 256){ int e = (i + rot5) & 4095; lds[(e>>6)*65 + (e&63)] = gld(&ws[OFF_A+e]); }
      __syncthreads();
      if (tid < 64){
        float rs = 0.f;
#pragma unroll
        for (int j = 0; j < 64; ++j) rs += lds[tid*65+j];
        lds[4224+tid] = rs;
      }
      __syncthreads();
      float th = 0.f;
#pragma unroll
      for (int j = 0; j < 64; ++j) th = fmaxf(th, lds[4224+j]);
      if (th > 0.25f){
        ssc = (int)ceilf(log2f(th*4.0f));
        if (ssc < 1) ssc = 1;
        if (ssc > 24) ssc = 24;
      }
      const float scl = exp2f((float)(-ssc));
      for (int e = tid; e < 4096; e += 256) lds[(e>>6)*65 + (e&63)] *= scl;
      __syncthreads();
      float cur0 = (tid < 64) ? lds[bid*65+tid] : 0.f;
      if (tid < 64) lds[4288+tid] = cur0;
      float srow = cur0;
      __syncthreads();
      const float invf[7] = {0.5f, 1.0f/6.0f, 1.0f/24.0f, 1.0f/120.0f, 1.0f/720.0f, 1.0f/5040.0f, 1.0f/40320.0f};
#pragma unroll
      for (int k = 0; k < 7; ++k){
        float nv = 0.f;
        if (tid < 64){
#pragma unroll
          for (int m = 0; m < 64; ++m) nv += lds[4288+m]*lds[m*65+tid];
        }
        __syncthreads();
        if (tid < 64) lds[4288+tid] = nv;
        srow += nv*invf[k];
        __syncthreads();
      }
      const int pb = ssc & 1;
      if (tid < 64) gst(&ws[(pb ? OFF_S2 : OFF_S) + bid*64 + tid], srow);
      for (int i = tid; i < 4096; i += 256){ int e = (i + rot5) & 4095; lds[4352+e] = 2.0f*gld(&ws[OFF_WV+e]); }
      for (int q = 0; q < ssc; ++q){
        gsync64(bar, ++eps);
        const int src = (ssc - q) & 1;
        const int so = src ? OFF_S2 : OFF_S;
        const int dofs = src ? OFF_S : OFF_S2;
        for (int i = tid; i < 4096; i += 256){ int e = (i + rot5) & 4095; lds[(e>>6)*65 + (e&63)] = gld(&ws[so+e]); }
        __syncthreads();
        if (tid < 64) lds[4288+tid] = lds[bid*65+tid];
        __syncthreads();
        if (tid < 64){
          float nv = 0.f;
#pragma unroll
          for (int m = 0; m < 64; ++m) nv += lds[4288+m]*lds[m*65+tid];
          nv += 2.0f*lds[4288+tid];
          gst(&ws[dofs + bid*64 + tid], nv);
        }
        __syncthreads();
      }
    } else {
      for (int i = tid; i < 4096; i += 256){ int e = (i + rot) & 4095; lds[4352+e] = 2.0f*gld(&ws[OFF_WV+e]); }
    }
    gsync(bar, ++ep);

    // ---- phase 6: Gvec = 2w ∘ Eᵀ ; g2 = silu'(h2) ∘ (dec3ᵀ @ Gvec) (tagged G3 out) ----
    {
      for (int i = tid; i < 4096; i += 256){ int e = (i + rot) & 4095; lds[(e>>6)*65 + (e&63)] = gld(&ws[OFF_S+e]); }
      __syncthreads();
      if (tid < 64) lds[4160+tid] = lds[tid*65+tid];   // diag(S)
      for (int e = tid; e < 4096; e += 256){
        const int i = e >> 6, j = e & 63;
        float Eji = lds[j*65+i] + ((i==j) ? 1.0f : 0.0f);
        lds[4352+e] *= Eji;                            // (2*wv) * Eji (prestaged in P5)
      }
      __syncthreads();
      {
        float hh = 0.f;
#pragma unroll
        for (int k = 0; k < 64; ++k) hh += lds[4160+k];
        hh_reg = hh;
      }
      if (wid < 2){
        float sum = 0.f;
#pragma unroll
        for (int m = 0; m < 16; ++m){
          float4 gv = *(const float4*)&lds[4352 + 4*lane + 256*m];
          sum += dot4(wu[8+m], gv);
        }
        sum = wredsum(sum);
        if (lane == 0){
          const int r = bid*2 + wid;
          float h2v = lds[PERSIST+wid];                // persisted h2 from P3
          float sg = 1.0f/(1.0f+expf(-h2v));
          tst(&TG3[r], sum*(sg*(1.0f + h2v*(1.0f-sg))), dtag);
        }
      }
    }
    // NO grid barrier: P7 consumes tagged G3 directly

    // ---- phase 7: g = tanh' ∘ (dec12ᵀ @ g2) (waves 2,3); tagged-G3 staging ----
    {
      __syncthreads();   // protect lds[0..511] reuse within block
      {
        const int s0i = 2*tid, s1i = 2*tid+1;
        float x = 1.f;
        unsigned long long a, b;
        for (;;){
          a = tld(&TG3[s0i]);
          b = tld(&TG3[s1i]);
          if (__all(((int)(a>>32) >= dtag) && ((int)(b>>32) >= dtag))) break;
          spinfma(x);
        }
        sinkf(x);
        lds[s0i] = __uint_as_float((unsigned)a);
        lds[s1i] = __uint_as_float((unsigned)b);
      }
      __syncthreads();
      if (wid >= 2){
        float4 gv0 = *(const float4*)&lds[4*lane];
        float4 gv1 = *(const float4*)&lds[256 + 4*lane];
        const int r7l = (wid-2)*4;                     // local row index 0..7
#pragma unroll
        for (int q = 0; q < 4; ++q){
          float sum = dot4(wu[16+2*q], gv0) + dot4(wu[17+2*q], gv1);
          sum = wredsum(sum);
          if (lane == 0){
            float thv = lds[PERSIST+2 + r7l + q];      // own zth rows saved in P3
            gst(&ws[OFF_G + bid*8 + r7l + q], sum*(1.0f - thv*thv));
          }
        }
      }
    }
    gsync(bar, ++ep);
  }

  // ---- west pass 1: dec12 over all t ----
  {
    const int t = bid >> 2;
    const int quad = bid & 3;
    for (int e = tid; e < 2048; e += 256) lds[e] = tanhf(gld(&ws[OFF_TRAJ + t*2048 + e]));
    __syncthreads();
    const float tw = (float)(t+1);
    for (int q = 0; q < 32; ++q){
      const int r = quad*128 + wid*32 + q;
      const float* wrow = ws + OFF_D12W + (size_t)r*2052;
      const float4* wr = (const float4*)wrow;
      float sum = 0.f;
#pragma unroll
      for (int m = 0; m < 8; ++m){
        float4 wv = wr[lane + 64*m];
        float4 zv = *(const float4*)&lds[(lane + 64*m)*4];
        sum += wv.x*zv.x + wv.y*zv.y + wv.z*zv.z + wv.w*zv.w;
      }
      sum = wredsum(sum);
      if (lane == 0){
        sum += wrow[2048]*tw + ws[OFF_D12B+r];
        float sg = 1.0f/(1.0f+expf(-sum));
        gst(&ws[OFF_H3W + t*512 + r], sum*sg);
      }
    }
  }
  gsync(bar, ++ep);
  // ---- west pass 2: dec3 over all t ----
  {
    const int t = bid >> 2;
    const int quad = bid & 3;
    for (int e = tid; e < 512; e += 256) lds[e] = gld(&ws[OFF_H3W + t*512 + e]);
    __syncthreads();
    for (int q = 0; q < 256; ++q){
      const int r = quad*1024 + wid*256 + q;
      const float4* wr = (const float4*)(d3w + (size_t)r*512);
      float sum = 0.f;
#pragma unroll
      for (int m = 0; m < 2; ++m){
        float4 wv = wr[lane + 64*m];
        float4 hv = *(const float4*)&lds[(lane + 64*m)*4];
        sum += wv.x*hv.x + wv.y*hv.y + wv.z*hv.z + wv.w*hv.w;
      }
      sum = wredsum(sum);
      if (lane == 0) ws[OFF_WEST + t*4096 + r] = sum + d3b[r];   // cross-kernel only
    }
  }
}

// ---------------- output kernel: out[b,t] = x[b,t]@W_t + x[b,t-1]@L ----------------
__global__ void __launch_bounds__(256) k_out(const float* __restrict__ x,
        const float* __restrict__ ws, float* __restrict__ out)
{
  __shared__ __align__(16) float Wbuf[4096];
  __shared__ __align__(16) float Xbuf[64*65];
  const int tid = threadIdx.x;
  const int t  = blockIdx.x & 63;
  const int bb = blockIdx.x >> 6;
  const int k0 = (tid & 15)*4;
  const int b0 = (tid >> 4)*4;
  const float* xbase = x + ((size_t)bb*64)*4096;

  float acc[4][4];
#pragma unroll
  for (int j = 0; j < 4; ++j)
#pragma unroll
    for (int c = 0; c < 4; ++c) acc[j][c] = 0.f;

  for (int e = tid; e < 4096; e += 256) Wbuf[e] = ws[OFF_WEST + t*4096 + e];
  for (int e = tid; e < 4096; e += 256){ int row = e>>6, col = e&63; Xbuf[row*65+col] = xbase[(size_t)row*4096 + t*64 + col]; }
  __syncthreads();
  for (int d = 0; d < 64; ++d){
    float4 wv = *(const float4*)&Wbuf[d*64 + k0];
#pragma unroll
    for (int j = 0; j < 4; ++j){
      float xv = Xbuf[(b0+j)*65 + d];
      acc[j][0] += xv*wv.x; acc[j][1] += xv*wv.y; acc[j][2] += xv*wv.z; acc[j][3] += xv*wv.w;
    }
  }
  if (t > 0){
    __syncthreads();
    for (int e = tid; e < 4096; e += 256) Wbuf[e] = ws[OFF_LMAT + e];
    for (int e = tid; e < 4096; e += 256){ int row = e>>6, col = e&63; Xbuf[row*65+col] = xbase[(size_t)row*4096 + (t-1)*64 + col]; }
    __syncthreads();
    for (int d = 0; d < 64; ++d){
      float4 wv = *(const float4*)&Wbuf[d*64 + k0];
#pragma unroll
      for (int j = 0; j < 4; ++j){
        float xv = Xbuf[(b0+j)*65 + d];
        acc[j][0] += xv*wv.x; acc[j][1] += xv*wv.y; acc[j][2] += xv*wv.z; acc[j][3] += xv*wv.w;
      }
    }
  }
#pragma unroll
  for (int j = 0; j < 4; ++j){
    float4 o4; o4.x = acc[j][0]; o4.y = acc[j][1]; o4.z = acc[j][2]; o4.w = acc[j][3];
    *(float4*)&out[((size_t)(bb*64 + b0 + j))*4096 + t*64 + k0] = o4;
  }
}

// ---------------- host launcher ----------------
extern "C" void kernel_launch(void* const* d_in, const int* in_sizes, int n_in,
                              void* d_out, int out_size, void* d_ws, size_t ws_size,
                              hipStream_t stream) {
  (void)in_sizes; (void)n_in; (void)out_size; (void)ws_size;
  const float* x    = (const float*)d_in[0];
  const float* iit  = (const float*)d_in[1];
  const float* iis  = (const float*)d_in[2];
  const float* encw = (const float*)d_in[3];
  const float* encb = (const float*)d_in[4];
  const float* l1w  = (const float*)d_in[5];
  const float* l1b  = (const float*)d_in[6];
  const float* l2w  = (const float*)d_in[7];
  const float* l2b  = (const float*)d_in[8];
  const float* d1w  = (const float*)d_in[9];
  const float* d1b  = (const float*)d_in[10];
  const float* d2w  = (const float*)d_in[11];
  const float* d2b  = (const float*)d_in[12];
  const float* d3w  = (const float*)d_in[13];
  const float* d3b  = (const float*)d_in[14];
  const float* uw   = (const float*)d_in[15];
  const float* vw   = (const float*)d_in[16];
  float* out = (float*)d_out;
  float* ws  = (float*)d_ws;
  int* bar   = (int*)(ws + OFF_BAR);

  hipMemsetAsync(bar, 0, BAR_TOTAL*sizeof(int), stream);
  k_init_z0<<<1, 256, 0, stream>>>(iit, iis, encw, encb, ws);
  k_init_dec12<<<64, 256, 0, stream>>>(d1w, d1b, d2w, d2b, ws);
  k_tr12<<<dim3(65,16), 256, 0, stream>>>(ws);
  k_tr3<<<dim3(16,128), 256, 0, stream>>>(d3w, ws);
  k_init_lmat<<<16, 256, 0, stream>>>(uw, vw, ws);

  k_ode<<<NBLK, NTHR, 0, stream>>>(l1w, l1b, l2w, l2b, d3w, d3b, ws, bar);

  k_out<<<4096, 256, 0, stream>>>(x, ws, out);
}